// Round 1
// baseline (426.379 us; speedup 1.0000x reference)
//
#include <hip/hip_runtime.h>
#include <math.h>

// Problem constants (B=8, C=192, H=W=32)
#define BB 8
#define CC 192
#define LL 1024
#define DI 384          // d_inner
#define DT_RANK 12
#define NS 16           // D_STATE
#define XD 44           // dt_rank + 2*NS

// ---------------------------------------------------------------------------
// K1: W2[j,c'] = sum_c in_proj_w[j,c]*proj_w[c,c'];  bias2[j] = in_proj_w[j,:]·proj_b
// grid 768, block 192
__global__ void fuse_w_kernel(const float* __restrict__ in_proj_w,
                              const float* __restrict__ proj_w,
                              const float* __restrict__ proj_b,
                              float* __restrict__ W2, float* __restrict__ bias2) {
    int j = blockIdx.x;
    int cp = threadIdx.x;
    __shared__ float wrow[CC];
    wrow[cp] = in_proj_w[j * CC + cp];
    __syncthreads();
    float acc = 0.f;
#pragma unroll 4
    for (int c = 0; c < CC; ++c) acc = fmaf(wrow[c], proj_w[c * CC + cp], acc);
    W2[j * CC + cp] = acc;
    if (cp == 0) {
        float b = 0.f;
        for (int c = 0; c < CC; ++c) b = fmaf(wrow[c], proj_b[c], b);
        bias2[j] = b;
    }
}

// ---------------------------------------------------------------------------
// K2: xz[row, j] = sum_c x[b, c, l] * W2[j, c] + bias2[j]   (row = b*1024 + l)
// M=8192, N=768, K=192. grid (128,12), block 256, 64x64 tile, 4x4/thread.
__global__ __launch_bounds__(256) void gemm_xz(const float* __restrict__ x,
                                               const float* __restrict__ W2,
                                               const float* __restrict__ bias2,
                                               float* __restrict__ xz) {
    __shared__ float As[16][68];  // [k][l]
    __shared__ float Bs[16][68];  // [k][j]
    int r0 = blockIdx.x * 64;     // global row base
    int j0 = blockIdx.y * 64;
    int b  = r0 >> 10;
    int l0 = r0 & 1023;
    int tid = threadIdx.x;
    int tx = tid & 15;   // -> j (4 per thread)  [coalesced writes along j]
    int ty = tid >> 4;   // -> l (4 per thread)
    float acc[4][4] = {};
    const float* xb = x + b * CC * LL;
    for (int k0 = 0; k0 < CC; k0 += 16) {
        {   // A: x[b, k0+k, l0+l] -> As[k][l]
            int k = tid >> 4, l4 = (tid & 15) * 4;
            float4 v = *(const float4*)(&xb[(k0 + k) * LL + l0 + l4]);
            *(float4*)(&As[k][l4]) = v;
        }
        {   // B: W2[j0+j, k0+kc..] -> Bs[kc][j]
            int j = tid >> 2, kc = (tid & 3) * 4;
            float4 v = *(const float4*)(&W2[(j0 + j) * CC + k0 + kc]);
            Bs[kc + 0][j] = v.x; Bs[kc + 1][j] = v.y;
            Bs[kc + 2][j] = v.z; Bs[kc + 3][j] = v.w;
        }
        __syncthreads();
#pragma unroll
        for (int k = 0; k < 16; ++k) {
            float4 av = *(const float4*)(&As[k][ty * 4]);
            float4 bv = *(const float4*)(&Bs[k][tx * 4]);
            acc[0][0] = fmaf(av.x, bv.x, acc[0][0]);
            acc[0][1] = fmaf(av.x, bv.y, acc[0][1]);
            acc[0][2] = fmaf(av.x, bv.z, acc[0][2]);
            acc[0][3] = fmaf(av.x, bv.w, acc[0][3]);
            acc[1][0] = fmaf(av.y, bv.x, acc[1][0]);
            acc[1][1] = fmaf(av.y, bv.y, acc[1][1]);
            acc[1][2] = fmaf(av.y, bv.z, acc[1][2]);
            acc[1][3] = fmaf(av.y, bv.w, acc[1][3]);
            acc[2][0] = fmaf(av.z, bv.x, acc[2][0]);
            acc[2][1] = fmaf(av.z, bv.y, acc[2][1]);
            acc[2][2] = fmaf(av.z, bv.z, acc[2][2]);
            acc[2][3] = fmaf(av.z, bv.w, acc[2][3]);
            acc[3][0] = fmaf(av.w, bv.x, acc[3][0]);
            acc[3][1] = fmaf(av.w, bv.y, acc[3][1]);
            acc[3][2] = fmaf(av.w, bv.z, acc[3][2]);
            acc[3][3] = fmaf(av.w, bv.w, acc[3][3]);
        }
        __syncthreads();
    }
    float4 bv = *(const float4*)(&bias2[j0 + tx * 4]);
#pragma unroll
    for (int il = 0; il < 4; ++il) {
        int row = r0 + ty * 4 + il;
        float4 o;
        o.x = acc[il][0] + bv.x; o.y = acc[il][1] + bv.y;
        o.z = acc[il][2] + bv.z; o.w = acc[il][3] + bv.w;
        *(float4*)(&xz[row * 768 + j0 + tx * 4]) = o;
    }
}

// ---------------------------------------------------------------------------
// K3: causal depthwise conv (k=4) + silu.  xin = xz[:, :384]
// grid 12288, block 256 (one thread per (row,d))
__global__ void conv_silu(const float* __restrict__ xz,
                          const float* __restrict__ conv_w,
                          const float* __restrict__ conv_b,
                          float* __restrict__ xc) {
    int idx = blockIdx.x * 256 + threadIdx.x;   // 8192*384
    int d = idx % DI;
    int row = idx / DI;
    int l = row & 1023;
    float w0 = conv_w[d * 4 + 0], w1 = conv_w[d * 4 + 1];
    float w2 = conv_w[d * 4 + 2], w3 = conv_w[d * 4 + 3];
    float acc = conv_b[d];
    if (l >= 3) acc = fmaf(w0, xz[(row - 3) * 768 + d], acc);
    if (l >= 2) acc = fmaf(w1, xz[(row - 2) * 768 + d], acc);
    if (l >= 1) acc = fmaf(w2, xz[(row - 1) * 768 + d], acc);
    acc = fmaf(w3, xz[row * 768 + d], acc);
    // silu
    float s = acc / (1.f + expf(-acc));
    xc[idx] = s;
}

// ---------------------------------------------------------------------------
// K4: x_dbl = xc @ xproj_w^T  (N=44, K=384); dt = softplus(dtr @ dtproj_w^T + b)
// block handles 16 rows. grid 512, block 256.
__global__ __launch_bounds__(256) void xdbl_dt_kernel(const float* __restrict__ xc,
                                                      const float* __restrict__ xproj_w,
                                                      const float* __restrict__ dtproj_w,
                                                      const float* __restrict__ dtproj_b,
                                                      float* __restrict__ xdbl,
                                                      float* __restrict__ dt) {
    __shared__ float xcs[16][388];   // +4 pad: 2-way banks only
    __shared__ float dtwT[12][392];  // dtproj_w transposed [r][d]
    __shared__ float xdS[16][12];    // dtr slice
    int r0 = blockIdx.x * 16;
    int tid = threadIdx.x;
#pragma unroll
    for (int i = 0; i < 24; ++i) {
        int t = tid + i * 256;              // 6144 = 16*384
        xcs[t / DI][t % DI] = xc[(r0 + t / DI) * DI + (t % DI)];
    }
    for (int t = tid; t < DI * DT_RANK; t += 256)
        dtwT[t % DT_RANK][t / DT_RANK] = dtproj_w[t];
    __syncthreads();
    // phase 1: 704 = 16 rows * 44 outputs
    for (int e = tid; e < 16 * XD; e += 256) {
        int row = e & 15, r = e >> 4;
        const float4* wr = (const float4*)&xproj_w[r * DI];
        const float4* xr = (const float4*)&xcs[row][0];
        float acc = 0.f;
#pragma unroll 8
        for (int q = 0; q < DI / 4; ++q) {
            float4 a = xr[q], w = wr[q];
            acc = fmaf(a.x, w.x, acc); acc = fmaf(a.y, w.y, acc);
            acc = fmaf(a.z, w.z, acc); acc = fmaf(a.w, w.w, acc);
        }
        xdbl[(r0 + row) * XD + r] = acc;
        if (r < DT_RANK) xdS[row][r] = acc;
    }
    __syncthreads();
    // phase 2: dt[row, d] = softplus(sum_r xdS[row][r]*dtwT[r][d] + b[d])
#pragma unroll
    for (int i = 0; i < 24; ++i) {
        int t = tid + i * 256;
        int row = t / DI, d = t % DI;
        float acc = dtproj_b[d];
#pragma unroll
        for (int r = 0; r < DT_RANK; ++r) acc = fmaf(xdS[row][r], dtwT[r][d], acc);
        float sp = fmaxf(acc, 0.f) + log1pf(expf(-fabsf(acc)));
        dt[(r0 + row) * DI + d] = sp;
    }
}

// ---------------------------------------------------------------------------
// K5: sequential selective scan.  16 lanes per (b,d) (lane = state n),
// 4 (b,d) groups per wave. 768 waves total. DPP row_ror 16-lane reduction.
__device__ __forceinline__ float rsum16(float x) {
    int v;
    v = __float_as_int(x);
    x += __int_as_float(__builtin_amdgcn_update_dpp(0, v, 0x128, 0xF, 0xF, true)); // ror 8
    v = __float_as_int(x);
    x += __int_as_float(__builtin_amdgcn_update_dpp(0, v, 0x124, 0xF, 0xF, true)); // ror 4
    v = __float_as_int(x);
    x += __int_as_float(__builtin_amdgcn_update_dpp(0, v, 0x122, 0xF, 0xF, true)); // ror 2
    v = __float_as_int(x);
    x += __int_as_float(__builtin_amdgcn_update_dpp(0, v, 0x121, 0xF, 0xF, true)); // ror 1
    return x;
}

#define CH 8

__global__ __launch_bounds__(256) void scan_kernel(const float* __restrict__ dt,
                                                   const float* __restrict__ xc,
                                                   const float* __restrict__ xdbl,
                                                   const float* __restrict__ xz,
                                                   const float* __restrict__ A_log,
                                                   const float* __restrict__ Dp,
                                                   float* __restrict__ y) {
    int wave = (blockIdx.x << 2) + (threadIdx.x >> 6);  // 0..767
    int lane = threadIdx.x & 63;
    int b = wave / 96;
    int dgrp = wave % 96;
    int g = lane >> 4, n = lane & 15;
    int d = dgrp * 4 + g;
    int bL = b << 10;
    float a = -expf(A_log[d * NS + n]);
    float Dpv = Dp[d];
    float h = 0.f;

    float d0[CH], x0[CH], b0[CH], c0[CH], z0[CH];
    float d1[CH], x1[CH], b1[CH], c1[CH], z1[CH];

#define LOADC(dd, xx, bb, cc, zz, lb)                                   \
    _Pragma("unroll") for (int i = 0; i < CH; ++i) {                    \
        int row = bL + (lb) + i;                                        \
        dd[i] = dt[row * DI + d];                                       \
        xx[i] = xc[row * DI + d];                                       \
        bb[i] = xdbl[row * XD + DT_RANK + n];                           \
        cc[i] = xdbl[row * XD + DT_RANK + NS + n];                      \
        zz[i] = xz[row * 768 + DI + d];                                 \
    }

#define COMP(dd, xx, bb, cc, zz, lb)                                    \
    _Pragma("unroll") for (int i = 0; i < CH; ++i) {                    \
        float dtv = dd[i];                                              \
        float dA = expf(dtv * a);                                       \
        h = fmaf(dA, h, dtv * bb[i] * xx[i]);                           \
        float s = rsum16(h * cc[i]);                                    \
        float zv = zz[i];                                               \
        float sig = 1.f / (1.f + expf(-zv));                            \
        float yv = (s + xx[i] * Dpv) * (zv * sig);                      \
        if (n == 0) y[(bL + (lb) + i) * DI + d] = yv;                   \
    }

    LOADC(d0, x0, b0, c0, z0, 0);
    for (int c = 0; c < 128; c += 2) {
        int lb1 = (c + 1) * CH;
        int lb2 = (c + 2) * CH;
        int lb2c = lb2 < LL ? lb2 : (LL - CH);
        LOADC(d1, x1, b1, c1, z1, lb1);
        COMP(d0, x0, b0, c0, z0, c * CH);
        LOADC(d0, x0, b0, c0, z0, lb2c);
        COMP(d1, x1, b1, c1, z1, lb1);
    }
#undef LOADC
#undef COMP
}

// ---------------------------------------------------------------------------
// K6: out[b, c, l] = sum_d y[row, d] * out_w[c, d]
// M=8192 rows, N=192, K=384. grid (128,3), block 256.
__global__ __launch_bounds__(256) void gemm_out(const float* __restrict__ y,
                                                const float* __restrict__ out_w,
                                                float* __restrict__ out) {
    __shared__ float As[16][68];  // [k][l]
    __shared__ float Bs[16][68];  // [k][c]
    int r0 = blockIdx.x * 64;
    int c0 = blockIdx.y * 64;
    int b = r0 >> 10, l0 = r0 & 1023;
    int tid = threadIdx.x;
    int tx = tid & 15;   // -> l (coalesced output writes along l)
    int ty = tid >> 4;   // -> c
    float acc[4][4] = {};  // [ic][il]
    for (int k0 = 0; k0 < DI; k0 += 16) {
        {   // A: y[r0+lr, k0+kc..] -> As[kc][lr] (transpose)
            int lr = tid >> 2, kc = (tid & 3) * 4;
            float4 v = *(const float4*)(&y[(r0 + lr) * DI + k0 + kc]);
            As[kc + 0][lr] = v.x; As[kc + 1][lr] = v.y;
            As[kc + 2][lr] = v.z; As[kc + 3][lr] = v.w;
        }
        {   // B: out_w[c0+c, k0+kc..] -> Bs[kc][c]
            int c = tid >> 2, kc = (tid & 3) * 4;
            float4 v = *(const float4*)(&out_w[(c0 + c) * DI + k0 + kc]);
            Bs[kc + 0][c] = v.x; Bs[kc + 1][c] = v.y;
            Bs[kc + 2][c] = v.z; Bs[kc + 3][c] = v.w;
        }
        __syncthreads();
#pragma unroll
        for (int k = 0; k < 16; ++k) {
            float4 av = *(const float4*)(&As[k][tx * 4]);
            float4 bv = *(const float4*)(&Bs[k][ty * 4]);
            acc[0][0] = fmaf(bv.x, av.x, acc[0][0]);
            acc[0][1] = fmaf(bv.x, av.y, acc[0][1]);
            acc[0][2] = fmaf(bv.x, av.z, acc[0][2]);
            acc[0][3] = fmaf(bv.x, av.w, acc[0][3]);
            acc[1][0] = fmaf(bv.y, av.x, acc[1][0]);
            acc[1][1] = fmaf(bv.y, av.y, acc[1][1]);
            acc[1][2] = fmaf(bv.y, av.z, acc[1][2]);
            acc[1][3] = fmaf(bv.y, av.w, acc[1][3]);
            acc[2][0] = fmaf(bv.z, av.x, acc[2][0]);
            acc[2][1] = fmaf(bv.z, av.y, acc[2][1]);
            acc[2][2] = fmaf(bv.z, av.z, acc[2][2]);
            acc[2][3] = fmaf(bv.z, av.w, acc[2][3]);
            acc[3][0] = fmaf(bv.w, av.x, acc[3][0]);
            acc[3][1] = fmaf(bv.w, av.y, acc[3][1]);
            acc[3][2] = fmaf(bv.w, av.z, acc[3][2]);
            acc[3][3] = fmaf(bv.w, av.w, acc[3][3]);
        }
        __syncthreads();
    }
    float* ob = out + b * CC * LL;
#pragma unroll
    for (int ic = 0; ic < 4; ++ic) {
        float4 o;
        o.x = acc[ic][0]; o.y = acc[ic][1]; o.z = acc[ic][2]; o.w = acc[ic][3];
        *(float4*)(&ob[(c0 + ty * 4 + ic) * LL + l0 + tx * 4]) = o;
    }
}

// ---------------------------------------------------------------------------
extern "C" void kernel_launch(void* const* d_in, const int* in_sizes, int n_in,
                              void* d_out, int out_size, void* d_ws, size_t ws_size,
                              hipStream_t stream) {
    const float* x         = (const float*)d_in[0];
    const float* proj_w    = (const float*)d_in[1];
    const float* proj_b    = (const float*)d_in[2];
    const float* in_proj_w = (const float*)d_in[3];
    const float* conv_w    = (const float*)d_in[4];
    const float* conv_b    = (const float*)d_in[5];
    const float* xproj_w   = (const float*)d_in[6];
    const float* dtproj_w  = (const float*)d_in[7];
    const float* dtproj_b  = (const float*)d_in[8];
    const float* A_log     = (const float*)d_in[9];
    const float* Dp        = (const float*)d_in[10];
    const float* out_w     = (const float*)d_in[11];
    float* out = (float*)d_out;

    float* ws    = (float*)d_ws;
    float* W2    = ws;                    // 768*192   = 147456
    float* bias2 = W2 + 147456;           // 768
    float* xz    = bias2 + 768;           // 8192*768  = 6291456
    float* xc    = xz + 6291456;          // 8192*384  = 3145728
    float* xdbl  = xc + 3145728;          // 8192*44   = 360448
    float* dt    = xdbl + 360448;         // 8192*384  = 3145728
    float* y     = dt + 3145728;          // 8192*384  = 3145728
    // total ~65 MB of workspace

    fuse_w_kernel<<<768, 192, 0, stream>>>(in_proj_w, proj_w, proj_b, W2, bias2);
    gemm_xz<<<dim3(128, 12), 256, 0, stream>>>(x, W2, bias2, xz);
    conv_silu<<<12288, 256, 0, stream>>>(xz, conv_w, conv_b, xc);
    xdbl_dt_kernel<<<512, 256, 0, stream>>>(xc, xproj_w, dtproj_w, dtproj_b, xdbl, dt);
    scan_kernel<<<192, 256, 0, stream>>>(dt, xc, xdbl, xz, A_log, Dp, y);
    gemm_out<<<dim3(128, 3), 256, 0, stream>>>(y, out_w, out);
}

// Round 2
// 286.715 us; speedup vs baseline: 1.4871x; 1.4871x over previous
//
#include <hip/hip_runtime.h>
#include <math.h>

// Problem constants (B=8, C=192, H=W=32)
#define BB 8
#define CC 192
#define LL 1024
#define RT 8192         // total rows = BB*LL
#define DI 384          // d_inner
#define DT_RANK 12
#define NS 16           // D_STATE
#define NSEG 16
#define SEGL 64

// ---------------------------------------------------------------------------
// K1: W2[j,c'] = sum_c in_proj_w[j,c]*proj_w[c,c'];  bias2[j] = in_proj_w[j,:]·proj_b
__global__ void fuse_w_kernel(const float* __restrict__ in_proj_w,
                              const float* __restrict__ proj_w,
                              const float* __restrict__ proj_b,
                              float* __restrict__ W2, float* __restrict__ bias2) {
    int j = blockIdx.x;
    int cp = threadIdx.x;
    __shared__ float wrow[CC];
    wrow[cp] = in_proj_w[j * CC + cp];
    __syncthreads();
    float acc = 0.f;
#pragma unroll 4
    for (int c = 0; c < CC; ++c) acc = fmaf(wrow[c], proj_w[c * CC + cp], acc);
    W2[j * CC + cp] = acc;
    if (cp == 0) {
        float b = 0.f;
        for (int c = 0; c < CC; ++c) b = fmaf(wrow[c], proj_b[c], b);
        bias2[j] = b;
    }
}

// ---------------------------------------------------------------------------
// K2: xzT[j, row] = sum_c x[b, c, l] * W2[j, c] + bias2[j]   (row = b*1024+l)
// M=8192 rows, N=768 j, K=192. grid (128,12), block 256, 64x64 tile.
__global__ __launch_bounds__(256) void gemm_xz(const float* __restrict__ x,
                                               const float* __restrict__ W2,
                                               const float* __restrict__ bias2,
                                               float* __restrict__ xzT) {
    __shared__ float As[16][68];  // [k][row]
    __shared__ float Bs[16][68];  // [k][j]
    int r0 = blockIdx.x * 64;
    int j0 = blockIdx.y * 64;
    int b  = r0 >> 10;
    int l0 = r0 & 1023;
    int tid = threadIdx.x;
    int tx = tid & 15;   // -> row quad (coalesced writes along row)
    int ty = tid >> 4;   // -> j quad
    float acc[4][4] = {};  // [jc][rc]
    const float* xb = x + b * CC * LL;
    for (int k0 = 0; k0 < CC; k0 += 16) {
        {   // A: x[b, k0+k, l0+r] -> As[k][r]
            int k = tid >> 4, r4 = (tid & 15) * 4;
            float4 v = *(const float4*)(&xb[(k0 + k) * LL + l0 + r4]);
            *(float4*)(&As[k][r4]) = v;
        }
        {   // B: W2[j0+j, k0+kc..] -> Bs[kc][j]
            int j = tid >> 2, kc = (tid & 3) * 4;
            float4 v = *(const float4*)(&W2[(j0 + j) * CC + k0 + kc]);
            Bs[kc + 0][j] = v.x; Bs[kc + 1][j] = v.y;
            Bs[kc + 2][j] = v.z; Bs[kc + 3][j] = v.w;
        }
        __syncthreads();
#pragma unroll
        for (int k = 0; k < 16; ++k) {
            float4 av = *(const float4*)(&As[k][tx * 4]);
            float4 bv = *(const float4*)(&Bs[k][ty * 4]);
            acc[0][0] = fmaf(bv.x, av.x, acc[0][0]);
            acc[0][1] = fmaf(bv.x, av.y, acc[0][1]);
            acc[0][2] = fmaf(bv.x, av.z, acc[0][2]);
            acc[0][3] = fmaf(bv.x, av.w, acc[0][3]);
            acc[1][0] = fmaf(bv.y, av.x, acc[1][0]);
            acc[1][1] = fmaf(bv.y, av.y, acc[1][1]);
            acc[1][2] = fmaf(bv.y, av.z, acc[1][2]);
            acc[1][3] = fmaf(bv.y, av.w, acc[1][3]);
            acc[2][0] = fmaf(bv.z, av.x, acc[2][0]);
            acc[2][1] = fmaf(bv.z, av.y, acc[2][1]);
            acc[2][2] = fmaf(bv.z, av.z, acc[2][2]);
            acc[2][3] = fmaf(bv.z, av.w, acc[2][3]);
            acc[3][0] = fmaf(bv.w, av.x, acc[3][0]);
            acc[3][1] = fmaf(bv.w, av.y, acc[3][1]);
            acc[3][2] = fmaf(bv.w, av.z, acc[3][2]);
            acc[3][3] = fmaf(bv.w, av.w, acc[3][3]);
        }
        __syncthreads();
    }
#pragma unroll
    for (int jc = 0; jc < 4; ++jc) {
        int j = j0 + ty * 4 + jc;
        float bval = bias2[j];
        float4 o;
        o.x = acc[jc][0] + bval; o.y = acc[jc][1] + bval;
        o.z = acc[jc][2] + bval; o.w = acc[jc][3] + bval;
        *(float4*)(&xzT[j * RT + r0 + tx * 4]) = o;
    }
}

// ---------------------------------------------------------------------------
// K3: causal depthwise conv (k=4) + silu on transposed layout.
// thread handles (d, 4 rows). grid 3072, block 256. (384*8192/4/256)
__global__ void conv_silu(const float* __restrict__ xzT,
                          const float* __restrict__ conv_w,
                          const float* __restrict__ conv_b,
                          float* __restrict__ xcT) {
    int q = blockIdx.x * 256 + threadIdx.x;
    int d = q >> 11;              // 2048 quads per d
    int rq = (q & 2047) << 2;     // row offset within [0,8192)
    int l0 = rq & 1023;
    const float* base = xzT + d * RT + rq;
    float4 cur = *(const float4*)base;
    float4 prev = make_float4(0.f, 0.f, 0.f, 0.f);
    if (l0 != 0) prev = *(const float4*)(base - 4);
    float w0 = conv_w[d * 4 + 0], w1 = conv_w[d * 4 + 1];
    float w2 = conv_w[d * 4 + 2], w3 = conv_w[d * 4 + 3];
    float bb = conv_b[d];
    float a0 = bb + w3 * cur.x + w2 * prev.w + w1 * prev.z + w0 * prev.y;
    float a1 = bb + w3 * cur.y + w2 * cur.x  + w1 * prev.w + w0 * prev.z;
    float a2 = bb + w3 * cur.z + w2 * cur.y  + w1 * cur.x  + w0 * prev.w;
    float a3 = bb + w3 * cur.w + w2 * cur.z  + w1 * cur.y  + w0 * cur.x;
    float4 o;
    o.x = a0 / (1.f + expf(-a0));
    o.y = a1 / (1.f + expf(-a1));
    o.z = a2 / (1.f + expf(-a2));
    o.w = a3 / (1.f + expf(-a3));
    *(float4*)(xcT + d * RT + rq) = o;
}

// ---------------------------------------------------------------------------
// K4: x_dbl = xc @ xproj_w^T; split into BT[n][row], CT[n][row];
//     dt = softplus(dtr @ dtproj_w^T + b) -> dtT[d][row]. 16 rows per block.
__global__ __launch_bounds__(256) void xdbl_dt_kernel(const float* __restrict__ xcT,
                                                      const float* __restrict__ xproj_w,
                                                      const float* __restrict__ dtproj_w,
                                                      const float* __restrict__ dtproj_b,
                                                      float* __restrict__ BT,
                                                      float* __restrict__ CT,
                                                      float* __restrict__ dtT) {
    __shared__ float xcs[16][388];   // [row][d]
    __shared__ float dtwT[12][388];  // [r][d]
    __shared__ float xdS[16][12];
    int r0 = blockIdx.x * 16;
    int tid = threadIdx.x;
    // load xcT tile [384 d][16 rows] transposing into xcs[row][d]
#pragma unroll
    for (int it = 0; it < 24; ++it) {
        int t = tid + it * 256;      // 6144
        int dd = t >> 4, i = t & 15;
        xcs[i][dd] = xcT[dd * RT + r0 + i];
    }
    for (int t = tid; t < DI * DT_RANK; t += 256)
        dtwT[t % DT_RANK][t / DT_RANK] = dtproj_w[t];
    __syncthreads();
    // phase 1: 704 = 16 rows * 44 outputs
    for (int e = tid; e < 16 * 44; e += 256) {
        int row = e & 15, r = e >> 4;
        const float4* wr = (const float4*)&xproj_w[r * DI];
        const float4* xr = (const float4*)&xcs[row][0];
        float acc = 0.f;
#pragma unroll 8
        for (int qq = 0; qq < DI / 4; ++qq) {
            float4 a = xr[qq], w = wr[qq];
            acc = fmaf(a.x, w.x, acc); acc = fmaf(a.y, w.y, acc);
            acc = fmaf(a.z, w.z, acc); acc = fmaf(a.w, w.w, acc);
        }
        if (r < DT_RANK)      xdS[row][r] = acc;
        else if (r < DT_RANK + NS) BT[(r - DT_RANK) * RT + r0 + row] = acc;
        else                  CT[(r - DT_RANK - NS) * RT + r0 + row] = acc;
    }
    __syncthreads();
    // phase 2: dtT[d, row] = softplus(sum_r xdS[row][r]*dtwT[r][d] + b[d])
#pragma unroll
    for (int it = 0; it < 24; ++it) {
        int t = tid + it * 256;
        int row = t & 15, d = t >> 4;
        float acc = dtproj_b[d];
#pragma unroll
        for (int r = 0; r < DT_RANK; ++r) acc = fmaf(xdS[row][r], dtwT[r][d], acc);
        float sp = fmaxf(acc, 0.f) + log1pf(expf(-fabsf(acc)));
        dtT[d * RT + r0 + row] = sp;
    }
}

// ---------------------------------------------------------------------------
// DPP 16-lane butterfly sum (lane-group = state index n)
__device__ __forceinline__ float rsum16(float x) {
    int v;
    v = __float_as_int(x);
    x += __int_as_float(__builtin_amdgcn_update_dpp(0, v, 0x128, 0xF, 0xF, true)); // ror 8
    v = __float_as_int(x);
    x += __int_as_float(__builtin_amdgcn_update_dpp(0, v, 0x124, 0xF, 0xF, true)); // ror 4
    v = __float_as_int(x);
    x += __int_as_float(__builtin_amdgcn_update_dpp(0, v, 0x122, 0xF, 0xF, true)); // ror 2
    v = __float_as_int(x);
    x += __int_as_float(__builtin_amdgcn_update_dpp(0, v, 0x121, 0xF, 0xF, true)); // ror 1
    return x;
}

// ---------------------------------------------------------------------------
// K5a: per-segment scan from h=0; emit P = prod(dA), Hf = final h.
// grid (16 seg, 24 dblk, 8 b), block 256 = 16 d x 16 n.
__global__ __launch_bounds__(256) void scan_part1(const float* __restrict__ dtT,
                                                  const float* __restrict__ xcT,
                                                  const float* __restrict__ BT,
                                                  const float* __restrict__ A_log,
                                                  float* __restrict__ P,
                                                  float* __restrict__ Hf) {
    __shared__ float dt_s[16][17], xc_s[16][17], B_s[16][17];
    int seg = blockIdx.x, d0 = blockIdx.y * 16, b = blockIdx.z;
    int row0 = b * LL + seg * SEGL;
    int tid = threadIdx.x;
    int lane = tid & 63;
    int n = lane & 15;
    int dl = ((tid >> 6) << 2) | (lane >> 4);
    int d = d0 + dl;
    int tdd = tid >> 4, ti = tid & 15;
    float a = -expf(A_log[d * NS + n]);
    float h = 0.f, Pacc = 1.f;
    for (int ch = 0; ch < 4; ++ch) {
        int r = row0 + ch * 16;
        dt_s[tdd][ti] = dtT[(d0 + tdd) * RT + r + ti];
        xc_s[tdd][ti] = xcT[(d0 + tdd) * RT + r + ti];
        B_s[tdd][ti]  = BT[tdd * RT + r + ti];
        __syncthreads();
#pragma unroll
        for (int i = 0; i < 16; ++i) {
            float dtv = dt_s[dl][i];
            float e = expf(dtv * a);
            Pacc *= e;
            h = fmaf(e, h, dtv * B_s[n][i] * xc_s[dl][i]);
        }
        __syncthreads();
    }
    int idx = ((seg * BB + b) * DI + d) * NS + n;
    P[idx] = Pacc;
    Hf[idx] = h;
}

// ---------------------------------------------------------------------------
// K5b: scan the 16 segment summaries; write h_init into P in place.
__global__ __launch_bounds__(256) void scan_mid(float* __restrict__ P,
                                                const float* __restrict__ Hf) {
    int t = blockIdx.x * 256 + threadIdx.x;   // 49152 = BB*DI*NS
    float h = 0.f;
#pragma unroll
    for (int s = 0; s < NSEG; ++s) {
        int off = s * (BB * DI * NS) + t;
        float p = P[off], f = Hf[off];
        P[off] = h;          // h_init for segment s
        h = fmaf(p, h, f);
    }
}

// ---------------------------------------------------------------------------
// K5c: rescan each segment from h_init; full epilogue; write yT[d][row].
// NOTE: yT aliases dtT (each block reads its dt tile before overwriting it).
__global__ __launch_bounds__(256) void scan_part2(const float* __restrict__ dtT,
                                                  const float* __restrict__ xcT,
                                                  const float* __restrict__ BT,
                                                  const float* __restrict__ CT,
                                                  const float* __restrict__ xzT,
                                                  const float* __restrict__ Hinit,
                                                  const float* __restrict__ A_log,
                                                  const float* __restrict__ Dp,
                                                  float* __restrict__ yT) {
    __shared__ float dt_s[16][17], xc_s[16][17], B_s[16][17], C_s[16][17],
                     z_s[16][17], y_s[16][17];
    int seg = blockIdx.x, d0 = blockIdx.y * 16, b = blockIdx.z;
    int row0 = b * LL + seg * SEGL;
    int tid = threadIdx.x;
    int lane = tid & 63;
    int n = lane & 15;
    int dl = ((tid >> 6) << 2) | (lane >> 4);
    int d = d0 + dl;
    int tdd = tid >> 4, ti = tid & 15;
    float a = -expf(A_log[d * NS + n]);
    float Dpv = Dp[d];
    float h = Hinit[((seg * BB + b) * DI + d) * NS + n];
    for (int ch = 0; ch < 4; ++ch) {
        int r = row0 + ch * 16;
        dt_s[tdd][ti] = dtT[(d0 + tdd) * RT + r + ti];
        xc_s[tdd][ti] = xcT[(d0 + tdd) * RT + r + ti];
        B_s[tdd][ti]  = BT[tdd * RT + r + ti];
        C_s[tdd][ti]  = CT[tdd * RT + r + ti];
        z_s[tdd][ti]  = xzT[(DI + d0 + tdd) * RT + r + ti];
        __syncthreads();
#pragma unroll
        for (int i = 0; i < 16; ++i) {
            float dtv = dt_s[dl][i];
            float e = expf(dtv * a);
            h = fmaf(e, h, dtv * B_s[n][i] * xc_s[dl][i]);
            float s = rsum16(h * C_s[n][i]);
            if (n == 0) {
                float zv = z_s[dl][i];
                float sig = 1.f / (1.f + expf(-zv));
                y_s[dl][i] = (s + xc_s[dl][i] * Dpv) * (zv * sig);
            }
        }
        __syncthreads();
        yT[(d0 + tdd) * RT + r + ti] = y_s[tdd][ti];
        __syncthreads();
    }
}

// ---------------------------------------------------------------------------
// K6: out[b, c, l] = sum_d yT[d, row] * out_w[c, d]
__global__ __launch_bounds__(256) void gemm_out(const float* __restrict__ yT,
                                                const float* __restrict__ out_w,
                                                float* __restrict__ out) {
    __shared__ float As[16][68];  // [k][row]
    __shared__ float Bs[16][68];  // [k][c]
    int r0 = blockIdx.x * 64;
    int c0 = blockIdx.y * 64;
    int b = r0 >> 10, l0 = r0 & 1023;
    int tid = threadIdx.x;
    int tx = tid & 15;   // -> row
    int ty = tid >> 4;   // -> c
    float acc[4][4] = {};  // [cc][rc]
    for (int k0 = 0; k0 < DI; k0 += 16) {
        {   // A: yT[k0+k, r0+r..] -> As[k][r]  (direct, coalesced)
            int k = tid >> 4, r4 = (tid & 15) * 4;
            float4 v = *(const float4*)(&yT[(k0 + k) * RT + r0 + r4]);
            *(float4*)(&As[k][r4]) = v;
        }
        {   // B: out_w[c0+c, k0+kc..] -> Bs[kc][c]
            int c = tid >> 2, kc = (tid & 3) * 4;
            float4 v = *(const float4*)(&out_w[(c0 + c) * DI + k0 + kc]);
            Bs[kc + 0][c] = v.x; Bs[kc + 1][c] = v.y;
            Bs[kc + 2][c] = v.z; Bs[kc + 3][c] = v.w;
        }
        __syncthreads();
#pragma unroll
        for (int k = 0; k < 16; ++k) {
            float4 av = *(const float4*)(&As[k][tx * 4]);
            float4 bv = *(const float4*)(&Bs[k][ty * 4]);
            acc[0][0] = fmaf(bv.x, av.x, acc[0][0]);
            acc[0][1] = fmaf(bv.x, av.y, acc[0][1]);
            acc[0][2] = fmaf(bv.x, av.z, acc[0][2]);
            acc[0][3] = fmaf(bv.x, av.w, acc[0][3]);
            acc[1][0] = fmaf(bv.y, av.x, acc[1][0]);
            acc[1][1] = fmaf(bv.y, av.y, acc[1][1]);
            acc[1][2] = fmaf(bv.y, av.z, acc[1][2]);
            acc[1][3] = fmaf(bv.y, av.w, acc[1][3]);
            acc[2][0] = fmaf(bv.z, av.x, acc[2][0]);
            acc[2][1] = fmaf(bv.z, av.y, acc[2][1]);
            acc[2][2] = fmaf(bv.z, av.z, acc[2][2]);
            acc[2][3] = fmaf(bv.z, av.w, acc[2][3]);
            acc[3][0] = fmaf(bv.w, av.x, acc[3][0]);
            acc[3][1] = fmaf(bv.w, av.y, acc[3][1]);
            acc[3][2] = fmaf(bv.w, av.z, acc[3][2]);
            acc[3][3] = fmaf(bv.w, av.w, acc[3][3]);
        }
        __syncthreads();
    }
    float* ob = out + b * CC * LL;
#pragma unroll
    for (int ic = 0; ic < 4; ++ic) {
        float4 o;
        o.x = acc[ic][0]; o.y = acc[ic][1]; o.z = acc[ic][2]; o.w = acc[ic][3];
        *(float4*)(&ob[(c0 + ty * 4 + ic) * LL + l0 + tx * 4]) = o;
    }
}

// ---------------------------------------------------------------------------
extern "C" void kernel_launch(void* const* d_in, const int* in_sizes, int n_in,
                              void* d_out, int out_size, void* d_ws, size_t ws_size,
                              hipStream_t stream) {
    const float* x         = (const float*)d_in[0];
    const float* proj_w    = (const float*)d_in[1];
    const float* proj_b    = (const float*)d_in[2];
    const float* in_proj_w = (const float*)d_in[3];
    const float* conv_w    = (const float*)d_in[4];
    const float* conv_b    = (const float*)d_in[5];
    const float* xproj_w   = (const float*)d_in[6];
    const float* dtproj_w  = (const float*)d_in[7];
    const float* dtproj_b  = (const float*)d_in[8];
    const float* A_log     = (const float*)d_in[9];
    const float* Dp        = (const float*)d_in[10];
    const float* out_w     = (const float*)d_in[11];
    float* out = (float*)d_out;

    float* ws    = (float*)d_ws;
    float* W2    = ws;                    // 147456
    float* bias2 = W2 + 147456;           // 768
    float* xzT   = bias2 + 768;           // 768*8192  = 6291456
    float* xcT   = xzT + 6291456;         // 384*8192  = 3145728
    float* dtT   = xcT + 3145728;         // 384*8192  = 3145728  (aliased as yT)
    float* BT    = dtT + 3145728;         // 16*8192   = 131072
    float* CT    = BT + 131072;           // 131072
    float* P     = CT + 131072;           // 16*8*384*16 = 786432
    float* Hf    = P + 786432;            // 786432
    float* yT    = dtT;                   // alias: each scan_part2 block reads its
                                          // dt tile before overwriting with y
    // total 14,566,144 floats = 58.3 MB

    fuse_w_kernel<<<768, 192, 0, stream>>>(in_proj_w, proj_w, proj_b, W2, bias2);
    gemm_xz<<<dim3(128, 12), 256, 0, stream>>>(x, W2, bias2, xzT);
    conv_silu<<<3072, 256, 0, stream>>>(xzT, conv_w, conv_b, xcT);
    xdbl_dt_kernel<<<512, 256, 0, stream>>>(xcT, xproj_w, dtproj_w, dtproj_b, BT, CT, dtT);
    scan_part1<<<dim3(16, 24, 8), 256, 0, stream>>>(dtT, xcT, BT, A_log, P, Hf);
    scan_mid<<<192, 256, 0, stream>>>(P, Hf);
    scan_part2<<<dim3(16, 24, 8), 256, 0, stream>>>(dtT, xcT, BT, CT, xzT, P, A_log, Dp, yT);
    gemm_out<<<dim3(128, 3), 256, 0, stream>>>(yT, out_w, out);
}

// Round 3
// 239.560 us; speedup vs baseline: 1.7798x; 1.1968x over previous
//
#include <hip/hip_runtime.h>
#include <math.h>

// Problem constants (B=8, C=192, H=W=32)
#define BB 8
#define CC 192
#define LL 1024
#define RT 8192         // total rows = BB*LL
#define DI 384          // d_inner
#define DT_RANK 12
#define NS 16           // D_STATE
#define NSEG 16
#define SEGL 64

// ---------------------------------------------------------------------------
// K1: W2[j,c'] = sum_c in_proj_w[j,c]*proj_w[c,c'];  bias2[j] = in_proj_w[j,:]·proj_b
__global__ void fuse_w_kernel(const float* __restrict__ in_proj_w,
                              const float* __restrict__ proj_w,
                              const float* __restrict__ proj_b,
                              float* __restrict__ W2, float* __restrict__ bias2) {
    int j = blockIdx.x;
    int cp = threadIdx.x;
    __shared__ float wrow[CC];
    wrow[cp] = in_proj_w[j * CC + cp];
    __syncthreads();
    float acc = 0.f;
#pragma unroll 4
    for (int c = 0; c < CC; ++c) acc = fmaf(wrow[c], proj_w[c * CC + cp], acc);
    W2[j * CC + cp] = acc;
    if (cp == 0) {
        float b = 0.f;
        for (int c = 0; c < CC; ++c) b = fmaf(wrow[c], proj_b[c], b);
        bias2[j] = b;
    }
}

// ---------------------------------------------------------------------------
// K2: xzT[j, row] = sum_c x[b, c, l] * W2[j, c] + bias2[j]   (row = b*1024+l)
__global__ __launch_bounds__(256) void gemm_xz(const float* __restrict__ x,
                                               const float* __restrict__ W2,
                                               const float* __restrict__ bias2,
                                               float* __restrict__ xzT) {
    __shared__ float As[16][68];  // [k][row]
    __shared__ float Bs[16][68];  // [k][j]
    int r0 = blockIdx.x * 64;
    int j0 = blockIdx.y * 64;
    int b  = r0 >> 10;
    int l0 = r0 & 1023;
    int tid = threadIdx.x;
    int tx = tid & 15;   // -> row quad
    int ty = tid >> 4;   // -> j quad
    float acc[4][4] = {};  // [jc][rc]
    const float* xb = x + b * CC * LL;
    for (int k0 = 0; k0 < CC; k0 += 16) {
        {   // A: x[b, k0+k, l0+r] -> As[k][r]
            int k = tid >> 4, r4 = (tid & 15) * 4;
            float4 v = *(const float4*)(&xb[(k0 + k) * LL + l0 + r4]);
            *(float4*)(&As[k][r4]) = v;
        }
        {   // B: W2[j0+j, k0+kc..] -> Bs[kc][j]
            int j = tid >> 2, kc = (tid & 3) * 4;
            float4 v = *(const float4*)(&W2[(j0 + j) * CC + k0 + kc]);
            Bs[kc + 0][j] = v.x; Bs[kc + 1][j] = v.y;
            Bs[kc + 2][j] = v.z; Bs[kc + 3][j] = v.w;
        }
        __syncthreads();
#pragma unroll
        for (int k = 0; k < 16; ++k) {
            float4 av = *(const float4*)(&As[k][tx * 4]);
            float4 bv = *(const float4*)(&Bs[k][ty * 4]);
            acc[0][0] = fmaf(bv.x, av.x, acc[0][0]);
            acc[0][1] = fmaf(bv.x, av.y, acc[0][1]);
            acc[0][2] = fmaf(bv.x, av.z, acc[0][2]);
            acc[0][3] = fmaf(bv.x, av.w, acc[0][3]);
            acc[1][0] = fmaf(bv.y, av.x, acc[1][0]);
            acc[1][1] = fmaf(bv.y, av.y, acc[1][1]);
            acc[1][2] = fmaf(bv.y, av.z, acc[1][2]);
            acc[1][3] = fmaf(bv.y, av.w, acc[1][3]);
            acc[2][0] = fmaf(bv.z, av.x, acc[2][0]);
            acc[2][1] = fmaf(bv.z, av.y, acc[2][1]);
            acc[2][2] = fmaf(bv.z, av.z, acc[2][2]);
            acc[2][3] = fmaf(bv.z, av.w, acc[2][3]);
            acc[3][0] = fmaf(bv.w, av.x, acc[3][0]);
            acc[3][1] = fmaf(bv.w, av.y, acc[3][1]);
            acc[3][2] = fmaf(bv.w, av.z, acc[3][2]);
            acc[3][3] = fmaf(bv.w, av.w, acc[3][3]);
        }
        __syncthreads();
    }
#pragma unroll
    for (int jc = 0; jc < 4; ++jc) {
        int j = j0 + ty * 4 + jc;
        float bval = bias2[j];
        float4 o;
        o.x = acc[jc][0] + bval; o.y = acc[jc][1] + bval;
        o.z = acc[jc][2] + bval; o.w = acc[jc][3] + bval;
        *(float4*)(&xzT[j * RT + r0 + tx * 4]) = o;
    }
}

// ---------------------------------------------------------------------------
// K3: d<384: causal depthwise conv (k=4) + silu -> xcT.
//     d>=384: silu(z) in place in xzT (becomes zsT).
// grid 6144, block 256.
__global__ void conv_silu(float* __restrict__ xzT,
                          const float* __restrict__ conv_w,
                          const float* __restrict__ conv_b,
                          float* __restrict__ xcT) {
    int q = blockIdx.x * 256 + threadIdx.x;
    int d = q >> 11;              // 2048 quads per channel
    int rq = (q & 2047) << 2;
    if (d < DI) {
        int l0 = rq & 1023;
        const float* base = xzT + d * RT + rq;
        float4 cur = *(const float4*)base;
        float4 prev = make_float4(0.f, 0.f, 0.f, 0.f);
        if (l0 != 0) prev = *(const float4*)(base - 4);
        float w0 = conv_w[d * 4 + 0], w1 = conv_w[d * 4 + 1];
        float w2 = conv_w[d * 4 + 2], w3 = conv_w[d * 4 + 3];
        float bb = conv_b[d];
        float a0 = bb + w3 * cur.x + w2 * prev.w + w1 * prev.z + w0 * prev.y;
        float a1 = bb + w3 * cur.y + w2 * cur.x  + w1 * prev.w + w0 * prev.z;
        float a2 = bb + w3 * cur.z + w2 * cur.y  + w1 * cur.x  + w0 * prev.w;
        float a3 = bb + w3 * cur.w + w2 * cur.z  + w1 * cur.y  + w0 * cur.x;
        float4 o;
        o.x = __fdividef(a0, 1.f + __expf(-a0));
        o.y = __fdividef(a1, 1.f + __expf(-a1));
        o.z = __fdividef(a2, 1.f + __expf(-a2));
        o.w = __fdividef(a3, 1.f + __expf(-a3));
        *(float4*)(xcT + d * RT + rq) = o;
    } else {
        float* base = xzT + d * RT + rq;
        float4 v = *(const float4*)base;
        float4 o;
        o.x = __fdividef(v.x, 1.f + __expf(-v.x));
        o.y = __fdividef(v.y, 1.f + __expf(-v.y));
        o.z = __fdividef(v.z, 1.f + __expf(-v.z));
        o.w = __fdividef(v.w, 1.f + __expf(-v.w));
        *(float4*)base = o;
    }
}

// ---------------------------------------------------------------------------
// K4a: skinny GEMM  xdT[m][row] = sum_k xproj_w[m][k] * xcT[k][row]
// M=44 (rows 0-11 dtr, 12-27 B, 28-43 C), N=8192, K=384.
// grid (128 coltiles, 2 mhalves), block 512 (64 cols x 8 mgroups x 3 m).
__global__ __launch_bounds__(512) void xproj_gemm(const float* __restrict__ xcT,
                                                  const float* __restrict__ aw,
                                                  float* __restrict__ xdT) {
    __shared__ float Bs[32][64];
    int col0 = blockIdx.x * 64;
    int tid = threadIdx.x;
    int col = tid & 63, mg = tid >> 6;          // mg wave-uniform -> scalar A loads
    int mb = blockIdx.y * 24 + mg * 3;
    const float* a0 = aw + min(mb + 0, 43) * DI;
    const float* a1 = aw + min(mb + 1, 43) * DI;
    const float* a2 = aw + min(mb + 2, 43) * DI;
    float acc0 = 0.f, acc1 = 0.f, acc2 = 0.f;
    int ks = tid >> 4, c4 = (tid & 15) * 4;
    for (int k0 = 0; k0 < DI; k0 += 32) {
        *(float4*)&Bs[ks][c4] = *(const float4*)&xcT[(k0 + ks) * RT + col0 + c4];
        __syncthreads();
#pragma unroll
        for (int k = 0; k < 32; ++k) {
            float bv = Bs[k][col];
            acc0 = fmaf(a0[k0 + k], bv, acc0);
            acc1 = fmaf(a1[k0 + k], bv, acc1);
            acc2 = fmaf(a2[k0 + k], bv, acc2);
        }
        __syncthreads();
    }
    if (mb + 0 < 44) xdT[(mb + 0) * RT + col0 + col] = acc0;
    if (mb + 1 < 44) xdT[(mb + 1) * RT + col0 + col] = acc1;
    if (mb + 2 < 44) xdT[(mb + 2) * RT + col0 + col] = acc2;
}

// ---------------------------------------------------------------------------
// K4b: dtT[d][row] = softplus(sum_r dtrT[r][row] * w[d][r] + b[d])
// grid (128 coltiles, 3 dblocks), block 512 (64 cols x 8 mg x 16 d).
__global__ __launch_bounds__(512) void dtproj_kernel(const float* __restrict__ dtrT,
                                                     const float* __restrict__ w,
                                                     const float* __restrict__ bvec,
                                                     float* __restrict__ dtT) {
    int col0 = blockIdx.x * 64;
    int tid = threadIdx.x;
    int col = tid & 63, mg = tid >> 6;
    int d0 = blockIdx.y * 128 + mg * 16;
    float rv[DT_RANK];
#pragma unroll
    for (int rr = 0; rr < DT_RANK; ++rr) rv[rr] = dtrT[rr * RT + col0 + col];
#pragma unroll
    for (int dd = 0; dd < 16; ++dd) {
        int d = d0 + dd;
        float acc = bvec[d];
#pragma unroll
        for (int rr = 0; rr < DT_RANK; ++rr) acc = fmaf(rv[rr], w[d * DT_RANK + rr], acc);
        float sp = fmaxf(acc, 0.f) + __logf(1.f + __expf(-fabsf(acc)));
        dtT[d * RT + col0 + col] = sp;
    }
}

// ---------------------------------------------------------------------------
// DPP 16-lane butterfly sum (lane-group = state index n)
__device__ __forceinline__ float rsum16(float x) {
    int v;
    v = __float_as_int(x);
    x += __int_as_float(__builtin_amdgcn_update_dpp(0, v, 0x128, 0xF, 0xF, true)); // ror 8
    v = __float_as_int(x);
    x += __int_as_float(__builtin_amdgcn_update_dpp(0, v, 0x124, 0xF, 0xF, true)); // ror 4
    v = __float_as_int(x);
    x += __int_as_float(__builtin_amdgcn_update_dpp(0, v, 0x122, 0xF, 0xF, true)); // ror 2
    v = __float_as_int(x);
    x += __int_as_float(__builtin_amdgcn_update_dpp(0, v, 0x121, 0xF, 0xF, true)); // ror 1
    return x;
}

// ---------------------------------------------------------------------------
// K5a: per-segment scan from h=0; emit P = prod(dA), Hf = final h.
__global__ __launch_bounds__(256) void scan_part1(const float* __restrict__ dtT,
                                                  const float* __restrict__ xcT,
                                                  const float* __restrict__ BT,
                                                  const float* __restrict__ A_log,
                                                  float* __restrict__ P,
                                                  float* __restrict__ Hf) {
    __shared__ float dt_s[16][17], g_s[16][17], B_s[16][17];
    int seg = blockIdx.x, d0 = blockIdx.y * 16, b = blockIdx.z;
    int row0 = b * LL + seg * SEGL;
    int tid = threadIdx.x;
    int lane = tid & 63;
    int n = lane & 15;
    int dl = ((tid >> 6) << 2) | (lane >> 4);
    int tdd = tid >> 4, ti = tid & 15;
    float a = -__expf(A_log[(d0 + dl) * NS + n]);
    float h = 0.f, Pacc = 1.f;
    for (int ch = 0; ch < 4; ++ch) {
        int r = row0 + ch * 16;
        float dtv = dtT[(d0 + tdd) * RT + r + ti];
        float xv  = xcT[(d0 + tdd) * RT + r + ti];
        dt_s[tdd][ti] = dtv;
        g_s[tdd][ti]  = dtv * xv;
        B_s[tdd][ti]  = BT[tdd * RT + r + ti];
        __syncthreads();
#pragma unroll
        for (int i = 0; i < 16; ++i) {
            float e = __expf(dt_s[dl][i] * a);
            Pacc *= e;
            h = fmaf(e, h, g_s[dl][i] * B_s[n][i]);
        }
        __syncthreads();
    }
    int idx = ((seg * BB + b) * DI + d0 + dl) * NS + n;
    P[idx] = Pacc;
    Hf[idx] = h;
}

// ---------------------------------------------------------------------------
// K5b: scan the 16 segment summaries; write h_init into P in place.
__global__ __launch_bounds__(256) void scan_mid(float* __restrict__ P,
                                                const float* __restrict__ Hf) {
    int t = blockIdx.x * 256 + threadIdx.x;   // 49152 = BB*DI*NS
    float h = 0.f;
#pragma unroll
    for (int s = 0; s < NSEG; ++s) {
        int off = s * (BB * DI * NS) + t;
        float p = P[off], f = Hf[off];
        P[off] = h;
        h = fmaf(p, h, f);
    }
}

// ---------------------------------------------------------------------------
// K5c: rescan each segment from h_init; rotating lane-capture epilogue.
// yT aliases dtT (each block reads its dt tile before overwriting it).
__global__ __launch_bounds__(256) void scan_part2(const float* __restrict__ dtT,
                                                  const float* __restrict__ xcT,
                                                  const float* __restrict__ BT,
                                                  const float* __restrict__ CT,
                                                  const float* __restrict__ zsT,
                                                  const float* __restrict__ Hinit,
                                                  const float* __restrict__ A_log,
                                                  const float* __restrict__ Dp,
                                                  float* __restrict__ yT) {
    __shared__ float dt_s[16][17], g_s[16][17], xc_s[16][17], B_s[16][17],
                     C_s[16][17], zs_s[16][17], y_s[16][17];
    int seg = blockIdx.x, d0 = blockIdx.y * 16, b = blockIdx.z;
    int row0 = b * LL + seg * SEGL;
    int tid = threadIdx.x;
    int lane = tid & 63;
    int n = lane & 15;
    int dl = ((tid >> 6) << 2) | (lane >> 4);
    int d = d0 + dl;
    int tdd = tid >> 4, ti = tid & 15;
    float a = -__expf(A_log[d * NS + n]);
    float Dpv = Dp[d];
    float h = Hinit[((seg * BB + b) * DI + d) * NS + n];
    for (int ch = 0; ch < 4; ++ch) {
        int r = row0 + ch * 16;
        float dtv = dtT[(d0 + tdd) * RT + r + ti];
        float xv  = xcT[(d0 + tdd) * RT + r + ti];
        dt_s[tdd][ti] = dtv;
        g_s[tdd][ti]  = dtv * xv;
        xc_s[tdd][ti] = xv;
        B_s[tdd][ti]  = BT[tdd * RT + r + ti];
        C_s[tdd][ti]  = CT[tdd * RT + r + ti];
        zs_s[tdd][ti] = zsT[(d0 + tdd) * RT + r + ti];
        __syncthreads();
        float scap = 0.f;
#pragma unroll
        for (int i = 0; i < 16; ++i) {
            float e = __expf(dt_s[dl][i] * a);
            h = fmaf(e, h, g_s[dl][i] * B_s[n][i]);
            float s = rsum16(h * C_s[n][i]);
            scap = (n == i) ? s : scap;   // lane n keeps row r+n's sum
        }
        // lane (dl, n) owns row r+n of channel d0+dl
        y_s[dl][n] = fmaf(xc_s[dl][n], Dpv, scap) * zs_s[dl][n];
        __syncthreads();
        yT[(d0 + tdd) * RT + r + ti] = y_s[tdd][ti];
        // next stage's writes are to dt_s.. (safe); y_s protected by next barrier
    }
}

// ---------------------------------------------------------------------------
// K6: out[b, c, l] = sum_d yT[d, row] * out_w[c, d]
__global__ __launch_bounds__(256) void gemm_out(const float* __restrict__ yT,
                                                const float* __restrict__ out_w,
                                                float* __restrict__ out) {
    __shared__ float As[16][68];  // [k][row]
    __shared__ float Bs[16][68];  // [k][c]
    int r0 = blockIdx.x * 64;
    int c0 = blockIdx.y * 64;
    int b = r0 >> 10, l0 = r0 & 1023;
    int tid = threadIdx.x;
    int tx = tid & 15;   // -> row
    int ty = tid >> 4;   // -> c
    float acc[4][4] = {};  // [cc][rc]
    for (int k0 = 0; k0 < DI; k0 += 16) {
        {   // A: yT[k0+k, r0+r..] -> As[k][r]
            int k = tid >> 4, r4 = (tid & 15) * 4;
            float4 v = *(const float4*)(&yT[(k0 + k) * RT + r0 + r4]);
            *(float4*)(&As[k][r4]) = v;
        }
        {   // B: out_w[c0+c, k0+kc..] -> Bs[kc][c]
            int c = tid >> 2, kc = (tid & 3) * 4;
            float4 v = *(const float4*)(&out_w[(c0 + c) * DI + k0 + kc]);
            Bs[kc + 0][c] = v.x; Bs[kc + 1][c] = v.y;
            Bs[kc + 2][c] = v.z; Bs[kc + 3][c] = v.w;
        }
        __syncthreads();
#pragma unroll
        for (int k = 0; k < 16; ++k) {
            float4 av = *(const float4*)(&As[k][tx * 4]);
            float4 bv = *(const float4*)(&Bs[k][ty * 4]);
            acc[0][0] = fmaf(bv.x, av.x, acc[0][0]);
            acc[0][1] = fmaf(bv.x, av.y, acc[0][1]);
            acc[0][2] = fmaf(bv.x, av.z, acc[0][2]);
            acc[0][3] = fmaf(bv.x, av.w, acc[0][3]);
            acc[1][0] = fmaf(bv.y, av.x, acc[1][0]);
            acc[1][1] = fmaf(bv.y, av.y, acc[1][1]);
            acc[1][2] = fmaf(bv.y, av.z, acc[1][2]);
            acc[1][3] = fmaf(bv.y, av.w, acc[1][3]);
            acc[2][0] = fmaf(bv.z, av.x, acc[2][0]);
            acc[2][1] = fmaf(bv.z, av.y, acc[2][1]);
            acc[2][2] = fmaf(bv.z, av.z, acc[2][2]);
            acc[2][3] = fmaf(bv.z, av.w, acc[2][3]);
            acc[3][0] = fmaf(bv.w, av.x, acc[3][0]);
            acc[3][1] = fmaf(bv.w, av.y, acc[3][1]);
            acc[3][2] = fmaf(bv.w, av.z, acc[3][2]);
            acc[3][3] = fmaf(bv.w, av.w, acc[3][3]);
        }
        __syncthreads();
    }
    float* ob = out + b * CC * LL;
#pragma unroll
    for (int ic = 0; ic < 4; ++ic) {
        float4 o;
        o.x = acc[ic][0]; o.y = acc[ic][1]; o.z = acc[ic][2]; o.w = acc[ic][3];
        *(float4*)(&ob[(c0 + ty * 4 + ic) * LL + l0 + tx * 4]) = o;
    }
}

// ---------------------------------------------------------------------------
extern "C" void kernel_launch(void* const* d_in, const int* in_sizes, int n_in,
                              void* d_out, int out_size, void* d_ws, size_t ws_size,
                              hipStream_t stream) {
    const float* x         = (const float*)d_in[0];
    const float* proj_w    = (const float*)d_in[1];
    const float* proj_b    = (const float*)d_in[2];
    const float* in_proj_w = (const float*)d_in[3];
    const float* conv_w    = (const float*)d_in[4];
    const float* conv_b    = (const float*)d_in[5];
    const float* xproj_w   = (const float*)d_in[6];
    const float* dtproj_w  = (const float*)d_in[7];
    const float* dtproj_b  = (const float*)d_in[8];
    const float* A_log     = (const float*)d_in[9];
    const float* Dp        = (const float*)d_in[10];
    const float* out_w     = (const float*)d_in[11];
    float* out = (float*)d_out;

    float* ws    = (float*)d_ws;
    float* W2    = ws;                    // 147456
    float* bias2 = W2 + 147456;           // 768
    float* xzT   = bias2 + 768;           // 768*8192 = 6291456
    float* xcT   = xzT + 6291456;         // 3145728
    float* dtT   = xcT + 3145728;         // 3145728 (aliased as yT)
    float* xdT   = dtT + 3145728;         // 44*8192 = 360448
    float* P     = xdT + 360448;          // 786432
    float* Hf    = P + 786432;            // 786432
    // total 14,664,448 floats = 58.7 MB
    float* dtrT = xdT;                    // rows 0-11
    float* BT   = xdT + 12 * RT;          // rows 12-27
    float* CT   = xdT + 28 * RT;          // rows 28-43
    float* zsT  = xzT + DI * RT;          // z half, silu'd in place by conv_silu
    float* yT   = dtT;

    fuse_w_kernel<<<768, 192, 0, stream>>>(in_proj_w, proj_w, proj_b, W2, bias2);
    gemm_xz<<<dim3(128, 12), 256, 0, stream>>>(x, W2, bias2, xzT);
    conv_silu<<<6144, 256, 0, stream>>>(xzT, conv_w, conv_b, xcT);
    xproj_gemm<<<dim3(128, 2), 512, 0, stream>>>(xcT, xproj_w, xdT);
    dtproj_kernel<<<dim3(128, 3), 512, 0, stream>>>(dtrT, dtproj_w, dtproj_b, dtT);
    scan_part1<<<dim3(16, 24, 8), 256, 0, stream>>>(dtT, xcT, BT, A_log, P, Hf);
    scan_mid<<<192, 256, 0, stream>>>(P, Hf);
    scan_part2<<<dim3(16, 24, 8), 256, 0, stream>>>(dtT, xcT, BT, CT, zsT, P, A_log, Dp, yT);
    gemm_out<<<dim3(128, 3), 256, 0, stream>>>(yT, out_w, out);
}